// Round 6
// baseline (316.396 us; speedup 1.0000x reference)
//
#include <hip/hip_runtime.h>
#include <hip/hip_bf16.h>
#include <stdint.h>

#define N_NODES 50000
#define N_EDGES 800000
#define HDIM 64
#define SCAN_N (N_NODES + 1)

// ---- workspace layout (CSR path) ----
#define MSG_BYTES  ((size_t)N_EDGES * HDIM * 2)          // 102,400,000 bf16 messages
#define INT_OFF    MSG_BYTES
#define DEG_OFF    (INT_OFF)
#define OFFS_OFF   (INT_OFF + 204800)
#define POS_OFF    (INT_OFF + 409600)
#define MSUM_OFF   (INT_OFF + 614400)
#define WS_NEED    (MSUM_OFF + (size_t)N_NODES * HDIM * 4)   // ~115.8 MB

typedef __attribute__((ext_vector_type(8))) short short8;
typedef __attribute__((ext_vector_type(4))) float floatx4;

__device__ __forceinline__ float bf2f(unsigned short u) {
    union { unsigned int i; float f; } v; v.i = ((unsigned int)u) << 16; return v.f;
}
__device__ __forceinline__ unsigned short f2bf(float f) {
    __hip_bfloat16 h = __float2bfloat16(f);
    return *reinterpret_cast<unsigned short*>(&h);
}

// Detect whether a float tensor was stored as bf16 (1) or f32 (0).
__device__ __forceinline__ int detect_is_bf16(const unsigned short* p) {
    int cnt = 0;
    #pragma unroll
    for (int i = 0; i < 64; ++i) {
        unsigned short b = p[i];
        int e = (b >> 7) & 0xFF;
        cnt += ((e >= 97 && e <= 157) || (b & 0x7FFF) == 0) ? 1 : 0;
    }
    return cnt >= 56;
}

__device__ __forceinline__ float getf(const void* p, unsigned int i, int isb) {
    return isb ? bf2f(((const unsigned short*)p)[i]) : ((const float*)p)[i];
}

__device__ __forceinline__ short8 get8bf(const void* p, unsigned int i, int isb) {
    if (isb) {
        return *reinterpret_cast<const short8*>((const short*)p + i);
    } else {
        const float4 f0 = *reinterpret_cast<const float4*>((const float*)p + i);
        const float4 f1 = *reinterpret_cast<const float4*>((const float*)p + i + 4);
        short8 a;
        a[0] = (short)f2bf(f0.x); a[1] = (short)f2bf(f0.y);
        a[2] = (short)f2bf(f0.z); a[3] = (short)f2bf(f0.w);
        a[4] = (short)f2bf(f1.x); a[5] = (short)f2bf(f1.y);
        a[6] = (short)f2bf(f1.z); a[7] = (short)f2bf(f1.w);
        return a;
    }
}

#define COMPILER_FENCE() asm volatile("" ::: "memory")
#define WAIT_LDS() __builtin_amdgcn_s_waitcnt(0xC07F)   // lgkmcnt(0) only

// ---------------------------------------------------------------------------
// CSR build: histogram + 2-level exclusive scan
// ---------------------------------------------------------------------------
__global__ void hist_kernel(const int* __restrict__ dst, int* __restrict__ deg) {
    for (int e = blockIdx.x * blockDim.x + threadIdx.x; e < N_EDGES;
         e += gridDim.x * blockDim.x)
        atomicAdd(&deg[dst[e]], 1);
}

__global__ void scan1_kernel(const int* __restrict__ deg, int* __restrict__ part) {
    __shared__ int s[1024];
    int g = blockIdx.x * 1024 + threadIdx.x;
    s[threadIdx.x] = (g < SCAN_N) ? deg[g] : 0;
    __syncthreads();
    for (int off = 512; off > 0; off >>= 1) {
        if (threadIdx.x < off) s[threadIdx.x] += s[threadIdx.x + off];
        __syncthreads();
    }
    if (threadIdx.x == 0) part[blockIdx.x] = s[0];
}

__global__ void scan2_kernel(int* __restrict__ part, int nparts) {
    if (threadIdx.x == 0) {
        int run = 0;
        for (int i = 0; i < nparts; ++i) { int t = part[i]; part[i] = run; run += t; }
    }
}

__global__ void scan3_kernel(const int* __restrict__ deg, const int* __restrict__ part,
                             int* __restrict__ offs, int* __restrict__ pos) {
    __shared__ int s[1024];
    int g = blockIdx.x * 1024 + threadIdx.x;
    int v = (g < SCAN_N) ? deg[g] : 0;
    s[threadIdx.x] = v;
    __syncthreads();
    for (int off = 1; off < 1024; off <<= 1) {     // Hillis-Steele inclusive
        int t = (threadIdx.x >= off) ? s[threadIdx.x - off] : 0;
        __syncthreads();
        s[threadIdx.x] += t;
        __syncthreads();
    }
    int excl = s[threadIdx.x] - v + part[blockIdx.x];
    if (g < SCAN_N) { offs[g] = excl; pos[g] = excl; }
}

// ---------------------------------------------------------------------------
// Edge kernel (templated): per wave, a 16-edge MFMA M-tile.
// CSR=true : claim slot with ONE int atomic per edge; write 128B bf16 message
//            row with 2 dwordx4 stores (no f32 atomics at all).
// CSR=false: round-5 fallback, f32 atomics into msum.
// ---------------------------------------------------------------------------
template <bool CSR>
__global__ __launch_bounds__(256, 2) void edge_kernel(
    const void* __restrict__ feat, const void* __restrict__ xpos,
    const int* __restrict__ src, const int* __restrict__ dst,
    const void* __restrict__ W1, const void* __restrict__ b1,
    const void* __restrict__ W2, const void* __restrict__ b2,
    const void* __restrict__ we, const void* __restrict__ be,
    float* __restrict__ msum, unsigned int msum_cap,
    unsigned short* __restrict__ msg, int* __restrict__ pos)
{
    __shared__ __align__(16) short sA2[4][16][72];

    const int isb  = detect_is_bf16((const unsigned short*)feat);
    const int tid  = threadIdx.x;
    const int wave = tid >> 6;
    const int lane = tid & 63;
    const int l15  = lane & 15;
    const int quad = lane >> 4;

    short8 bw1[4][4];
    #pragma unroll
    for (int c = 0; c < 4; ++c)
        #pragma unroll
        for (int nt = 0; nt < 4; ++nt) {
            short8 b;
            #pragma unroll
            for (int j = 0; j < 8; ++j)
                b[j] = (short)f2bf(getf(W1, (c * 32 + quad * 8 + j) * 64 + nt * 16 + l15, isb));
            bw1[c][nt] = b;
        }
    short8 bw2[2][4];
    #pragma unroll
    for (int c = 0; c < 2; ++c)
        #pragma unroll
        for (int nt = 0; nt < 4; ++nt) {
            short8 b;
            #pragma unroll
            for (int j = 0; j < 8; ++j)
                b[j] = (short)f2bf(getf(W2, (c * 32 + quad * 8 + j) * 64 + nt * 16 + l15, isb));
            bw2[c][nt] = b;
        }
    float b1r[4], w1lr[4], b2r[4], wer[4];
    #pragma unroll
    for (int nt = 0; nt < 4; ++nt) {
        int n = nt * 16 + l15;
        b1r[nt]  = getf(b1, n, isb);
        w1lr[nt] = getf(W1, 128 * 64 + n, isb);
        b2r[nt]  = getf(b2, n, isb);
        wer[nt]  = getf(we, n, isb);
    }
    const float ber = getf(be, 0, isb);
    const int rowb = quad * 4;

    const int ntiles = N_EDGES / 64;
    for (int t = blockIdx.x; t < ntiles; t += gridDim.x) {
        const int ebase = t * 64 + wave * 16;

        int sidx = 0, didx = 0, slotv = 0;
        float sqd = 0.f;
        if (lane < 16) {
            int e = ebase + lane;
            sidx = src[e];
            didx = dst[e];
            if (CSR) slotv = atomicAdd(&pos[didx], 1);   // early: latency hidden
            float dx = getf(xpos, sidx * 3 + 0, isb) - getf(xpos, didx * 3 + 0, isb);
            float dy = getf(xpos, sidx * 3 + 1, isb) - getf(xpos, didx * 3 + 1, isb);
            float dz = getf(xpos, sidx * 3 + 2, isb) - getf(xpos, didx * 3 + 2, isb);
            sqd = dx * dx + dy * dy + dz * dz;
        }
        const int sn     = __shfl(sidx, l15);
        const int dn_row = __shfl(didx, l15);

        // ---- layer 1 ----
        floatx4 acc[4];
        #pragma unroll
        for (int nt = 0; nt < 4; ++nt) acc[nt] = (floatx4){0.f, 0.f, 0.f, 0.f};
        #pragma unroll
        for (int c = 0; c < 4; ++c) {
            const int node = (c < 2) ? sn : dn_row;
            short8 a = get8bf(feat, node * 64 + (c & 1) * 32 + quad * 8, isb);
            #pragma unroll
            for (int nt = 0; nt < 4; ++nt)
                acc[nt] = __builtin_amdgcn_mfma_f32_16x16x32_bf16(a, bw1[c][nt], acc[nt], 0, 0, 0);
        }

        // ---- epilogue 1 -> LDS ----
        float sq[4];
        #pragma unroll
        for (int r = 0; r < 4; ++r) sq[r] = __shfl(sqd, rowb + r);
        #pragma unroll
        for (int nt = 0; nt < 4; ++nt)
            #pragma unroll
            for (int r = 0; r < 4; ++r) {
                float v = fmaxf(acc[nt][r] + b1r[nt] + sq[r] * w1lr[nt], 0.f);
                sA2[wave][rowb + r][nt * 16 + l15] = (short)f2bf(v);
            }
        COMPILER_FENCE();
        WAIT_LDS();

        // ---- layer 2 ----
        floatx4 acc2[4];
        #pragma unroll
        for (int nt = 0; nt < 4; ++nt) acc2[nt] = (floatx4){0.f, 0.f, 0.f, 0.f};
        #pragma unroll
        for (int c = 0; c < 2; ++c) {
            short8 a = *reinterpret_cast<const short8*>(&sA2[wave][l15][c * 32 + quad * 8]);
            #pragma unroll
            for (int nt = 0; nt < 4; ++nt)
                acc2[nt] = __builtin_amdgcn_mfma_f32_16x16x32_bf16(a, bw2[c][nt], acc2[nt], 0, 0, 0);
        }
        COMPILER_FENCE();

        // ---- epilogue 2: relu, gate ----
        float mval[4][4];
        float part[4] = {0.f, 0.f, 0.f, 0.f};
        #pragma unroll
        for (int nt = 0; nt < 4; ++nt)
            #pragma unroll
            for (int r = 0; r < 4; ++r) {
                float v = fmaxf(acc2[nt][r] + b2r[nt], 0.f);
                mval[nt][r] = v;
                part[r] += v * wer[nt];
            }
        #pragma unroll
        for (int off = 1; off < 16; off <<= 1)
            #pragma unroll
            for (int r = 0; r < 4; ++r) part[r] += __shfl_xor(part[r], off);
        float gate[4];
        #pragma unroll
        for (int r = 0; r < 4; ++r)
            gate[r] = 1.f / (1.f + __expf(-(part[r] + ber)));

        if (CSR) {
            // stage gated message rows in LDS (reuse sA2; layer-2 reads done)
            #pragma unroll
            for (int nt = 0; nt < 4; ++nt)
                #pragma unroll
                for (int r = 0; r < 4; ++r)
                    sA2[wave][rowb + r][nt * 16 + l15] = (short)f2bf(mval[nt][r] * gate[r]);
            COMPILER_FENCE();
            WAIT_LDS();
            // lane -> (row=l15, 32B chunk=quad); 2 dwordx4 stores per lane
            int slot_r = __shfl(slotv, l15);
            const short8 v0 = *reinterpret_cast<const short8*>(&sA2[wave][l15][quad * 16]);
            const short8 v1 = *reinterpret_cast<const short8*>(&sA2[wave][l15][quad * 16 + 8]);
            unsigned short* mp = msg + (size_t)slot_r * 64 + quad * 16;
            *reinterpret_cast<short8*>(mp)     = v0;
            *reinterpret_cast<short8*>(mp + 8) = v1;
            COMPILER_FENCE();
        } else {
            #pragma unroll
            for (int r = 0; r < 4; ++r) {
                int dn = __shfl(didx, rowb + r);
                unsigned int base = (unsigned int)dn * 64u;
                if (base + 64u <= msum_cap) {
                    #pragma unroll
                    for (int nt = 0; nt < 4; ++nt)
                        unsafeAtomicAdd(&msum[base + nt * 16 + l15], mval[nt][r] * gate[r]);
                }
            }
        }
    }
}

// ---------------------------------------------------------------------------
// CSR reduce: thread (node,quad) sums its node's contiguous message rows.
// ---------------------------------------------------------------------------
__global__ __launch_bounds__(256) void reduce_kernel(
    const unsigned short* __restrict__ msg, const int* __restrict__ offs,
    float* __restrict__ msum)
{
    int idx  = blockIdx.x * 256 + threadIdx.x;
    int node = idx >> 2, quad = idx & 3;
    if (node >= N_NODES) return;
    int s = offs[node], e = offs[node + 1];
    float acc[16];
    #pragma unroll
    for (int i = 0; i < 16; ++i) acc[i] = 0.f;
    for (int j = s; j < e; ++j) {
        const unsigned short* p = msg + (size_t)j * 64 + quad * 16;
        short8 a = *reinterpret_cast<const short8*>(p);
        short8 b = *reinterpret_cast<const short8*>(p + 8);
        #pragma unroll
        for (int i = 0; i < 8; ++i) {
            acc[i]     += bf2f((unsigned short)a[i]);
            acc[i + 8] += bf2f((unsigned short)b[i]);
        }
    }
    float* op = msum + (size_t)node * 64 + quad * 16;
    #pragma unroll
    for (int k = 0; k < 4; ++k) {
        float4 v = {acc[k * 4], acc[k * 4 + 1], acc[k * 4 + 2], acc[k * 4 + 3]};
        *reinterpret_cast<float4*>(op + k * 4) = v;
    }
}

// ---------------------------------------------------------------------------
// Node kernel (unchanged from round 5): per wave a 16-node MFMA M-tile.
// ---------------------------------------------------------------------------
__global__ __launch_bounds__(256, 2) void node_kernel(
    const float* __restrict__ msum, const void* __restrict__ feat,
    const void* __restrict__ U1, const void* __restrict__ c1v,
    const void* __restrict__ U2, const void* __restrict__ c2v,
    void* __restrict__ out, unsigned int msum_cap)
{
    __shared__ __align__(16) short sT[4][16][72];

    const int isb  = detect_is_bf16((const unsigned short*)feat);
    const int tid  = threadIdx.x;
    const int wave = tid >> 6;
    const int lane = tid & 63;
    const int l15  = lane & 15;
    const int quad = lane >> 4;

    short8 u1f[2][4], u2f[2][4];
    #pragma unroll
    for (int c = 0; c < 2; ++c)
        #pragma unroll
        for (int nt = 0; nt < 4; ++nt) {
            short8 a, b;
            #pragma unroll
            for (int j = 0; j < 8; ++j) {
                int k = c * 32 + quad * 8 + j, n = nt * 16 + l15;
                a[j] = (short)f2bf(getf(U1, k * 64 + n, isb));
                b[j] = (short)f2bf(getf(U2, k * 64 + n, isb));
            }
            u1f[c][nt] = a; u2f[c][nt] = b;
        }
    float c1r[4], c2r[4];
    #pragma unroll
    for (int nt = 0; nt < 4; ++nt) {
        c1r[nt] = getf(c1v, nt * 16 + l15, isb);
        c2r[nt] = getf(c2v, nt * 16 + l15, isb);
    }
    const int rowb = quad * 4;

    const int ntile = (N_NODES + 15) / 16;
    const int t = blockIdx.x * 4 + wave;
    if (t < ntile) {
        const int node = t * 16 + l15;

        short8 ah[2];
        #pragma unroll
        for (int c = 0; c < 2; ++c) {
            unsigned int off = (unsigned int)node * 64u + c * 32 + quad * 8;
            float hv[8];
            if (isb) {
                short8 fv = *reinterpret_cast<const short8*>((const short*)feat + off);
                #pragma unroll
                for (int j = 0; j < 8; ++j) hv[j] = bf2f((unsigned short)fv[j]);
            } else {
                float4 f0 = *reinterpret_cast<const float4*>((const float*)feat + off);
                float4 f1 = *reinterpret_cast<const float4*>((const float*)feat + off + 4);
                hv[0] = f0.x; hv[1] = f0.y; hv[2] = f0.z; hv[3] = f0.w;
                hv[4] = f1.x; hv[5] = f1.y; hv[6] = f1.z; hv[7] = f1.w;
            }
            float4 m0 = *reinterpret_cast<const float4*>(msum + off);
            float4 m1 = *reinterpret_cast<const float4*>(msum + off + 4);
            hv[0] += m0.x; hv[1] += m0.y; hv[2] += m0.z; hv[3] += m0.w;
            hv[4] += m1.x; hv[5] += m1.y; hv[6] += m1.z; hv[7] += m1.w;
            short8 a;
            #pragma unroll
            for (int j = 0; j < 8; ++j) a[j] = (short)f2bf(hv[j]);
            ah[c] = a;
        }

        floatx4 acc[4];
        #pragma unroll
        for (int nt = 0; nt < 4; ++nt) acc[nt] = (floatx4){0.f, 0.f, 0.f, 0.f};
        #pragma unroll
        for (int c = 0; c < 2; ++c)
            #pragma unroll
            for (int nt = 0; nt < 4; ++nt)
                acc[nt] = __builtin_amdgcn_mfma_f32_16x16x32_bf16(ah[c], u1f[c][nt], acc[nt], 0, 0, 0);

        #pragma unroll
        for (int nt = 0; nt < 4; ++nt)
            #pragma unroll
            for (int r = 0; r < 4; ++r) {
                float v = fmaxf(acc[nt][r] + c1r[nt], 0.f);
                sT[wave][rowb + r][nt * 16 + l15] = (short)f2bf(v);
            }
        COMPILER_FENCE();
        WAIT_LDS();

        floatx4 acc2[4];
        #pragma unroll
        for (int nt = 0; nt < 4; ++nt) acc2[nt] = (floatx4){0.f, 0.f, 0.f, 0.f};
        #pragma unroll
        for (int c = 0; c < 2; ++c) {
            short8 a = *reinterpret_cast<const short8*>(&sT[wave][l15][c * 32 + quad * 8]);
            #pragma unroll
            for (int nt = 0; nt < 4; ++nt)
                acc2[nt] = __builtin_amdgcn_mfma_f32_16x16x32_bf16(a, u2f[c][nt], acc2[nt], 0, 0, 0);
        }
        COMPILER_FENCE();

        #pragma unroll
        for (int r = 0; r < 4; ++r) {
            unsigned int row = (unsigned int)(t * 16 + rowb + r);
            #pragma unroll
            for (int nt = 0; nt < 4; ++nt) {
                unsigned int off = row * 64u + nt * 16 + l15;
                float v = acc2[nt][r] + c2r[nt] + getf(feat, off, isb);
                if (isb) ((unsigned short*)out)[off] = f2bf(v);
                else     ((float*)out)[off] = v;
            }
        }
    }
}

extern "C" void kernel_launch(void* const* d_in, const int* in_sizes, int n_in,
                              void* d_out, int out_size, void* d_ws, size_t ws_size,
                              hipStream_t stream) {
    const void* feat = d_in[0];
    const void* x    = d_in[1];
    const int* src   = (const int*)d_in[2];
    const int* dst   = (const int*)d_in[3];
    const void* W1   = d_in[4];
    const void* b1   = d_in[5];
    const void* W2   = d_in[6];
    const void* b2   = d_in[7];
    const void* we   = d_in[8];
    const void* be   = d_in[9];
    const void* U1   = d_in[10];
    const void* c1   = d_in[11];
    const void* U2   = d_in[12];
    const void* c2   = d_in[13];
    char* ws = (char*)d_ws;

    if (ws_size >= WS_NEED) {
        // ---------------- CSR scatter->gather path ----------------
        unsigned short* msg = (unsigned short*)(ws);
        int* deg   = (int*)(ws + DEG_OFF);
        int* offs  = (int*)(ws + OFFS_OFF);
        int* pos   = (int*)(ws + POS_OFF);
        float* msum = (float*)(ws + MSUM_OFF);

        hipMemsetAsync(ws + INT_OFF, 0, 614400, stream);   // deg (+ scratch ints)
        hist_kernel<<<1024, 256, 0, stream>>>(dst, deg);
        // 2-level exclusive scan over 50001 degrees; partials stored in offs
        scan1_kernel<<<49, 1024, 0, stream>>>(deg, offs + 51200 - 64);  // reuse tail as part[]
        scan2_kernel<<<1, 64, 0, stream>>>(offs + 51200 - 64, 49);
        scan3_kernel<<<49, 1024, 0, stream>>>(deg, offs + 51200 - 64, offs, pos);
        edge_kernel<true><<<2500, 256, 0, stream>>>(feat, x, src, dst, W1, b1, W2, b2,
                                                    we, be, msum, 0xFFFFFFFFu, msg, pos);
        reduce_kernel<<<(N_NODES * 4 + 255) / 256, 256, 0, stream>>>(msg, offs, msum);
        node_kernel<<<((N_NODES + 15) / 16 + 3) / 4, 256, 0, stream>>>(msum, feat, U1, c1,
                                                                       U2, c2, d_out, (unsigned int)(N_NODES * HDIM));
    } else {
        // ---------------- fallback: round-5 atomic path ----------------
        float* msum = (float*)ws;
        size_t need = (size_t)N_NODES * HDIM * sizeof(float);
        size_t clr  = need < ws_size ? need : ws_size;
        unsigned int cap = (unsigned int)(ws_size / sizeof(float));
        if (cap > (unsigned int)(N_NODES * HDIM)) cap = (unsigned int)(N_NODES * HDIM);

        hipMemsetAsync(msum, 0, clr, stream);
        edge_kernel<false><<<2500, 256, 0, stream>>>(feat, x, src, dst, W1, b1, W2, b2,
                                                     we, be, msum, cap, nullptr, nullptr);
        node_kernel<<<((N_NODES + 15) / 16 + 3) / 4, 256, 0, stream>>>(msum, feat, U1, c1,
                                                                       U2, c2, d_out, cap);
    }
}